// Round 7
// baseline (120.570 us; speedup 1.0000x reference)
//
#include <hip/hip_runtime.h>
#include <hip/hip_bf16.h>
#include <stdint.h>

#define TOKENS 16384   // N=4 * L=4096
#define LSEQ 4096
#define WPAD 72        // padded row length (shorts) for M/vw weight tiles

typedef short bf16x8 __attribute__((ext_vector_type(8)));
typedef float f32x4 __attribute__((ext_vector_type(4)));

typedef __attribute__((address_space(1))) void as1_t;
typedef __attribute__((address_space(3))) void as3_t;

__device__ __forceinline__ unsigned short f2bf(float x) {
  __hip_bfloat16 t = __float2bfloat16(x);
  return *reinterpret_cast<unsigned short*>(&t);
}

__device__ __forceinline__ bf16x8 pack8(float4 a, float4 b) {
  bf16x8 t;
  t[0] = (short)f2bf(a.x); t[1] = (short)f2bf(a.y);
  t[2] = (short)f2bf(a.z); t[3] = (short)f2bf(a.w);
  t[4] = (short)f2bf(b.x); t[5] = (short)f2bf(b.y);
  t[6] = (short)f2bf(b.z); t[7] = (short)f2bf(b.w);
  return t;
}

__device__ __forceinline__ void async16(const void* g, void* lds) {
  __builtin_amdgcn_global_load_lds((as1_t*)const_cast<void*>(g),
                                   (as3_t*)lds, 16, 0, 0);
}

// ---------------- fc_w f32 -> bf16 ----------------
__global__ __launch_bounds__(256) void cvt_bf16(const float* __restrict__ s,
                                                unsigned short* __restrict__ d,
                                                int n4) {
  int i = blockIdx.x * 256 + threadIdx.x;
  if (i < n4) {
    float4 f = ((const float4*)s)[i];
    union { unsigned short us[4]; uint2 u2; } pk;
    pk.us[0] = f2bf(f.x); pk.us[1] = f2bf(f.y);
    pk.us[2] = f2bf(f.z); pk.us[3] = f2bf(f.w);
    ((uint2*)d)[i] = pk.u2;
  }
}

// ---------------- prep: M[f][e] = sum_d qw[d][f]*kw[d][e]; vw -> bf16 ----------------
__global__ __launch_bounds__(1024) void prep_weights(
    const float* __restrict__ qw, const float* __restrict__ kw,
    const float* __restrict__ vw, unsigned short* __restrict__ Mout,
    unsigned short* __restrict__ vwout) {
  __shared__ float ql[4096], kl[4096];
  const int t = threadIdx.x;
  ((float4*)ql)[t] = ((const float4*)qw)[t];
  ((float4*)kl)[t] = ((const float4*)kw)[t];
  {
    float4 f = ((const float4*)vw)[t];
    union { unsigned short us[4]; uint2 u2; } pk;
    pk.us[0] = f2bf(f.x); pk.us[1] = f2bf(f.y);
    pk.us[2] = f2bf(f.z); pk.us[3] = f2bf(f.w);
    ((uint2*)vwout)[t] = pk.u2;
  }
  __syncthreads();
  const int f = t >> 4;            // 0..63  (q raw dim)
  const int e0 = (t & 15) * 4;     // 0..60  (k raw dim block)
  float acc0 = 0.f, acc1 = 0.f, acc2 = 0.f, acc3 = 0.f;
#pragma unroll 8
  for (int d = 0; d < 64; ++d) {
    const float qv = ql[d * 64 + f];
    const float4 kv = *(const float4*)&kl[d * 64 + e0];
    acc0 += qv * kv.x; acc1 += qv * kv.y; acc2 += qv * kv.z; acc3 += qv * kv.w;
  }
  union { unsigned short us[4]; uint2 u2; } pk;
  pk.us[0] = f2bf(acc0); pk.us[1] = f2bf(acc1);
  pk.us[2] = f2bf(acc2); pk.us[3] = f2bf(acc3);
  *(uint2*)&Mout[f * 64 + e0] = pk.u2;
}

// ---------------- fused attention: global_load_lds DMA pipeline ----------------
// 2 waves/block, wave-private double-buffered f32 stage (q,k,v 4KB each + mask 1KB),
// source-pre-swizzled (16B chunk idx ^= row&7) so frag ds_read_b128s are spread.
// Counted vmcnt (never drain-0 mid-loop). Compute path = R6-validated:
// mfma(fragA(X), fragA(Y)) = X @ Y^T; fragA: lane holds X[row=l&15][k=(l>>4)*8+j];
// C-layout: col=l&15, row=(l>>4)*4+r.
#define STG_BYTES 13312   // 3*4096 (q,k,v f32) + 1024 (mask)

__global__ __launch_bounds__(128) void attn7(
    const float* __restrict__ q, const float* __restrict__ k,
    const float* __restrict__ v, const int* __restrict__ mask,
    const unsigned short* __restrict__ Mg, const unsigned short* __restrict__ vwg,
    unsigned short* __restrict__ X) {
  __shared__ unsigned short Ml[64 * WPAD];     // 9216 B
  __shared__ unsigned short Vw[64 * WPAD];     // 9216 B
  __shared__ char stg_[2][2][STG_BYTES];       // [wave][buf] 53248 B
  __shared__ char scr_[2][2048];               // per-wave U/O scratch (swizzled)

  const int tid = threadIdx.x;
  const int l = tid & 63, w = tid >> 6;
  const int lr = l & 15, lg = l >> 4;
  char* scr = scr_[w];

  // ---- stage weights into LDS (block-wide, once) ----
  {
    const int row = tid >> 1, c0 = (tid & 1) * 32;
#pragma unroll
    for (int j = 0; j < 4; ++j) {
      *(uint4*)&Ml[row * WPAD + c0 + j * 8] = *(const uint4*)(Mg + row * 64 + c0 + j * 8);
      *(uint4*)&Vw[row * WPAD + c0 + j * 8] = *(const uint4*)(vwg + row * 64 + c0 + j * 8);
    }
  }
  __syncthreads();

  // ---- DMA issue: 13 global_load_lds per token (zero VGPR cost) ----
  auto issue = [&](int tok, char* dst) {
    const size_t tb = (size_t)tok * 1024;
#pragma unroll
    for (int i = 0; i < 4; ++i) {
      const int r = i * 4 + (l >> 4);
      const int se = r * 64 + (((l & 15) ^ (r & 7)) << 2);  // pre-swizzled source
      async16(q + tb + se, dst + i * 1024);
      async16(k + tb + se, dst + 4096 + i * 1024);
      async16(v + tb + se, dst + 8192 + i * 1024);
    }
    async16(mask + (size_t)tok * 256 + l * 4, dst + 12288);
  };

  const int tok0 = (blockIdx.x * 2 + w) * 8;
  issue(tok0, stg_[w][0]);

  const int r7 = lr & 7;
  const int fr0 = lr * 128 + ((lg * 16) ^ (r7 << 4));        // scr frag offsets (bf16)
  const int fr1 = lr * 128 + ((64 + lg * 16) ^ (r7 << 4));

#pragma unroll
  for (int t = 0; t < 8; ++t) {
    const int tok = tok0 + t;
    char* cur = stg_[w][t & 1];

    if (t < 7) {
      issue(tok + 1, stg_[w][(t + 1) & 1]);
      // 13 just-issued + <=2 prior stores may stay outstanding; cur's 13 must land
      asm volatile("s_waitcnt vmcnt(13)" ::: "memory");
    } else {
      asm volatile("s_waitcnt vmcnt(2)" ::: "memory");
    }
    __builtin_amdgcn_sched_barrier(0);

    // ---- mask + frag reads from swizzled f32 tiles ----
    const int4 mk4 = *(const int4*)(cur + 12288 + lr * 64 + lg * 16);
    auto ldfrag = [&](const char* base, int kc) -> bf16x8 {
      const int c0 = kc * 8 + 2 * lg;
      const float4 f0 = *(const float4*)(base + lr * 256 + (((c0) ^ r7) << 4));
      const float4 f1 = *(const float4*)(base + lr * 256 + (((c0 + 1) ^ r7) << 4));
      return pack8(f0, f1);
    };
    const bf16x8 aq0 = ldfrag(cur, 0),        aq1 = ldfrag(cur, 1);
    const bf16x8 ak0 = ldfrag(cur + 4096, 0), ak1 = ldfrag(cur + 4096, 1);
    const bf16x8 av0 = ldfrag(cur + 8192, 0), av1 = ldfrag(cur + 8192, 1);

    // ---- U = Rk @ M^T ; v4 = Rv @ vw^T ----
    f32x4 accu[4], accv[4];
#pragma unroll
    for (int n = 0; n < 4; ++n) {
      const int wrow = (n * 16 + lr) * WPAD;
      f32x4 z = {};
      const bf16x8 bm0 = *(const bf16x8*)&Ml[wrow + lg * 8];
      const bf16x8 bm1 = *(const bf16x8*)&Ml[wrow + 32 + lg * 8];
      accu[n] = __builtin_amdgcn_mfma_f32_16x16x32_bf16(ak0, bm0, z, 0, 0, 0);
      accu[n] = __builtin_amdgcn_mfma_f32_16x16x32_bf16(ak1, bm1, accu[n], 0, 0, 0);
      const bf16x8 bw0 = *(const bf16x8*)&Vw[wrow + lg * 8];
      const bf16x8 bw1 = *(const bf16x8*)&Vw[wrow + 32 + lg * 8];
      accv[n] = __builtin_amdgcn_mfma_f32_16x16x32_bf16(av0, bw0, z, 0, 0, 0);
      accv[n] = __builtin_amdgcn_mfma_f32_16x16x32_bf16(av1, bw1, accv[n], 0, 0, 0);
    }

    // ---- U -> swizzled scratch, re-read as A-frag, S^T = U @ Rq^T ----
#pragma unroll
    for (int n = 0; n < 4; ++n)
#pragma unroll
      for (int r = 0; r < 4; ++r) {
        const int row = lg * 4 + r;
        *(unsigned short*)(scr + row * 128 + ((32 * n + 2 * lr) ^ ((row & 7) << 4))) =
            f2bf(accu[n][r]);
      }
    const bf16x8 ua0 = *(const bf16x8*)(scr + fr0);
    const bf16x8 ua1 = *(const bf16x8*)(scr + fr1);
    f32x4 z4 = {};
    f32x4 st = __builtin_amdgcn_mfma_f32_16x16x32_bf16(ua0, aq0, z4, 0, 0, 0);
    st = __builtin_amdgcn_mfma_f32_16x16x32_bf16(ua1, aq1, st, 0, 0, 0);

    // ---- softmax over g (no max-subtraction: |S| small; masked -> 0) ----
    float e[4];
    float sm = 0.f;
    const int mks[4] = {mk4.x, mk4.y, mk4.z, mk4.w};
#pragma unroll
    for (int r = 0; r < 4; ++r) {
      e[r] = (mks[r] != 0) ? __expf(st[r] * 0.125f) : 0.f;
      sm += e[r];
    }
    sm += __shfl_xor(sm, 16);
    sm += __shfl_xor(sm, 32);
    const float inv = 1.0f / sm;
#pragma unroll
    for (int r = 0; r < 4; ++r) e[r] *= inv;

    // ---- PV A-frag (P[h=lr][g=lg*8+j], lanes lg>=2 zero) ----
    bf16x8 apv;
#pragma unroll
    for (int j = 0; j < 8; ++j) {
      const int srcg = (lg * 2 + (j >> 2)) & 3;
      const float pv = __shfl(e[j & 3], lr + srcg * 16, 64);
      apv[j] = (short)((lg < 2) ? f2bf(pv) : (unsigned short)0);
    }

    // ---- PV B-frags from accv via shuffles; O = P @ v4 ----
    const int s0 = lr + ((lg & 1) * 2) * 16;
    const int s1 = s0 + 16;
    f32x4 o[4];
#pragma unroll
    for (int n = 0; n < 4; ++n) {
      bf16x8 bv;
#pragma unroll
      for (int j = 0; j < 8; ++j) {
        const float xv = __shfl(accv[n][j & 3], (j < 4) ? s0 : s1, 64);
        bv[j] = (short)f2bf(xv);
      }
      f32x4 z = {};
      o[n] = __builtin_amdgcn_mfma_f32_16x16x32_bf16(apv, bv, z, 0, 0, 0);
    }

    // ---- O -> swizzled scratch -> vectorized X stores (2 per lane) ----
#pragma unroll
    for (int n = 0; n < 4; ++n)
#pragma unroll
      for (int r = 0; r < 4; ++r) {
        const int row = lg * 4 + r;
        *(unsigned short*)(scr + row * 128 + ((32 * n + 2 * lr) ^ ((row & 7) << 4))) =
            f2bf(o[n][r]);
      }
    const int nb = tok >> 12, lpos = tok & (LSEQ - 1);
#pragma unroll
    for (int it = 0; it < 2; ++it) {
      const int idx = it * 64 + l;
      const int h = idx >> 3, c = idx & 7;
      const uint4 val = *(const uint4*)(scr + h * 128 + ((c * 16) ^ ((h & 7) << 4)));
      *(uint4*)&X[((size_t)(nb * 16 + h) * LSEQ + lpos) * 64 + c * 8] = val;
    }
  }
}

// ---------------- final FC: OUT[16384x1024] = X @ fc_w^T + b (bf16 MFMA) ----------------
__global__ __launch_bounds__(256) void gemm_fc(const unsigned short* __restrict__ A,
                                               const unsigned short* __restrict__ B,
                                               const float* __restrict__ bias,
                                               float* __restrict__ C) {
  __shared__ unsigned short sA[128 * 32];
  __shared__ unsigned short sB[128 * 32];
  const int tid = threadIdx.x;
  const int l = tid & 63, w = tid >> 6;
  const int wr = w >> 1, wc = w & 1;

  const int bid = blockIdx.x;
  const int wg = (bid & 7) * 128 + (bid >> 3);
  const int tm = (wg >> 3) * 128;
  const int tn = (wg & 7) * 128;

  f32x4 acc[4][4] = {};

  const int r0 = w * 16 + (l >> 2);
  const int c8 = (l & 3) * 8;

  for (int kt = 0; kt < 32; ++kt) {
    const int k0 = kt * 32;
#pragma unroll
    for (int s = 0; s < 2; ++s) {
      async16(A + (size_t)(tm + s * 64 + r0) * 1024 + k0 + c8,
              (char*)sA + s * 4096 + w * 1024);
      async16(B + (size_t)(tn + s * 64 + r0) * 1024 + k0 + c8,
              (char*)sB + s * 4096 + w * 1024);
    }
    __syncthreads();

    bf16x8 af[4], bfr[4];
#pragma unroll
    for (int fi = 0; fi < 4; ++fi)
      af[fi] = *(const bf16x8*)((const char*)sA +
                                (wr * 64 + fi * 16 + (l & 15)) * 64 + (l >> 4) * 16);
#pragma unroll
    for (int fj = 0; fj < 4; ++fj)
      bfr[fj] = *(const bf16x8*)((const char*)sB +
                                 (wc * 64 + fj * 16 + (l & 15)) * 64 + (l >> 4) * 16);
#pragma unroll
    for (int fi = 0; fi < 4; ++fi)
#pragma unroll
      for (int fj = 0; fj < 4; ++fj)
        acc[fi][fj] = __builtin_amdgcn_mfma_f32_16x16x32_bf16(af[fi], bfr[fj],
                                                              acc[fi][fj], 0, 0, 0);
    __syncthreads();
  }

#pragma unroll
  for (int fj = 0; fj < 4; ++fj) {
    const int col = tn + wc * 64 + fj * 16 + (l & 15);
    const float bv = bias[col];
#pragma unroll
    for (int fi = 0; fi < 4; ++fi) {
#pragma unroll
      for (int r = 0; r < 4; ++r) {
        const int row = tm + wr * 64 + fi * 16 + (l >> 4) * 4 + r;
        C[(size_t)row * 1024 + col] = acc[fi][fj][r] + bv;
      }
    }
  }
}

extern "C" void kernel_launch(void* const* d_in, const int* in_sizes, int n_in,
                              void* d_out, int out_size, void* d_ws, size_t ws_size,
                              hipStream_t stream) {
  (void)in_sizes; (void)n_in; (void)out_size; (void)ws_size;
  const float* q   = (const float*)d_in[0];
  const float* k   = (const float*)d_in[1];
  const float* v   = (const float*)d_in[2];
  const int*  mask = (const int*)d_in[3];
  const float* qw  = (const float*)d_in[4];
  const float* kw  = (const float*)d_in[5];
  const float* vw  = (const float*)d_in[6];
  const float* fcw = (const float*)d_in[7];
  const float* fcb = (const float*)d_in[8];
  float* out = (float*)d_out;

  unsigned short* X   = (unsigned short*)d_ws;            // 16M bf16 = 32 MiB
  unsigned short* Wb  = X + (size_t)16 * 1024 * 1024;     // 1M bf16  =  2 MiB
  unsigned short* Mw  = Wb + (size_t)1024 * 1024;         // 4096 bf16 = 8 KiB
  unsigned short* vwb = Mw + 4096;                        // 4096 bf16 = 8 KiB

  cvt_bf16<<<dim3(1024), dim3(256), 0, stream>>>(fcw, Wb, 262144);
  prep_weights<<<dim3(1), dim3(1024), 0, stream>>>(qw, kw, vw, Mw, vwb);
  attn7<<<dim3(1024), dim3(128), 0, stream>>>(q, k, v, mask, Mw, vwb, X);
  gemm_fc<<<dim3(1024), dim3(256), 0, stream>>>(X, Wb, fcb, out);
}

// Round 8
// 116.143 us; speedup vs baseline: 1.0381x; 1.0381x over previous
//
#include <hip/hip_runtime.h>
#include <hip/hip_bf16.h>
#include <stdint.h>

#define TOKENS 16384   // N=4 * L=4096
#define LSEQ 4096
#define WPAD 72        // padded row length (shorts) used by prep consumers (gemm only)
#define NT 4           // tokens per wave

typedef short bf16x8 __attribute__((ext_vector_type(8)));
typedef float f32x4 __attribute__((ext_vector_type(4)));

typedef __attribute__((address_space(1))) void as1_t;
typedef __attribute__((address_space(3))) void as3_t;

__device__ __forceinline__ unsigned short f2bf(float x) {
  __hip_bfloat16 t = __float2bfloat16(x);
  return *reinterpret_cast<unsigned short*>(&t);
}

__device__ __forceinline__ bf16x8 pack8(float4 a, float4 b) {
  bf16x8 t;
  t[0] = (short)f2bf(a.x); t[1] = (short)f2bf(a.y);
  t[2] = (short)f2bf(a.z); t[3] = (short)f2bf(a.w);
  t[4] = (short)f2bf(b.x); t[5] = (short)f2bf(b.y);
  t[6] = (short)f2bf(b.z); t[7] = (short)f2bf(b.w);
  return t;
}

__device__ __forceinline__ void async16(const void* g, void* lds) {
  __builtin_amdgcn_global_load_lds((as1_t*)const_cast<void*>(g),
                                   (as3_t*)lds, 16, 0, 0);
}

// inline-asm 16B loads: compiler does NOT track these in vmcnt -> manual waits
__device__ __forceinline__ float4 aload(const float* p) {
  float4 r;
  asm volatile("global_load_dwordx4 %0, %1, off" : "=v"(r) : "v"(p));
  return r;
}
__device__ __forceinline__ int4 aloadi(const int* p) {
  int4 r;
  asm volatile("global_load_dwordx4 %0, %1, off" : "=v"(r) : "v"(p));
  return r;
}
#define WAITCNT(n) asm volatile("s_waitcnt vmcnt(" #n ")" ::: "memory")
#define SBAR() __builtin_amdgcn_sched_barrier(0)

// ---------------- fc_w f32 -> bf16 ----------------
__global__ __launch_bounds__(256) void cvt_bf16(const float* __restrict__ s,
                                                unsigned short* __restrict__ d,
                                                int n4) {
  int i = blockIdx.x * 256 + threadIdx.x;
  if (i < n4) {
    float4 f = ((const float4*)s)[i];
    union { unsigned short us[4]; uint2 u2; } pk;
    pk.us[0] = f2bf(f.x); pk.us[1] = f2bf(f.y);
    pk.us[2] = f2bf(f.z); pk.us[3] = f2bf(f.w);
    ((uint2*)d)[i] = pk.u2;
  }
}

// ---------------- prep: M[f][e] = sum_d qw[d][f]*kw[d][e]; vw -> bf16 ----------------
__global__ __launch_bounds__(1024) void prep_weights(
    const float* __restrict__ qw, const float* __restrict__ kw,
    const float* __restrict__ vw, unsigned short* __restrict__ Mout,
    unsigned short* __restrict__ vwout) {
  __shared__ float ql[4096], kl[4096];
  const int t = threadIdx.x;
  ((float4*)ql)[t] = ((const float4*)qw)[t];
  ((float4*)kl)[t] = ((const float4*)kw)[t];
  {
    float4 f = ((const float4*)vw)[t];
    union { unsigned short us[4]; uint2 u2; } pk;
    pk.us[0] = f2bf(f.x); pk.us[1] = f2bf(f.y);
    pk.us[2] = f2bf(f.z); pk.us[3] = f2bf(f.w);
    ((uint2*)vwout)[t] = pk.u2;
  }
  __syncthreads();
  const int f = t >> 4;            // 0..63  (q raw dim)
  const int e0 = (t & 15) * 4;     // 0..60  (k raw dim block)
  float acc0 = 0.f, acc1 = 0.f, acc2 = 0.f, acc3 = 0.f;
#pragma unroll 8
  for (int d = 0; d < 64; ++d) {
    const float qv = ql[d * 64 + f];
    const float4 kv = *(const float4*)&kl[d * 64 + e0];
    acc0 += qv * kv.x; acc1 += qv * kv.y; acc2 += qv * kv.z; acc3 += qv * kv.w;
  }
  union { unsigned short us[4]; uint2 u2; } pk;
  pk.us[0] = f2bf(acc0); pk.us[1] = f2bf(acc1);
  pk.us[2] = f2bf(acc2); pk.us[3] = f2bf(acc3);
  *(uint2*)&Mout[f * 64 + e0] = pk.u2;
}

// ---------------- fused attention: asm-pinned register loads, manual vmcnt ------------
// mfma(fragA(X), fragA(Y)) = X @ Y^T (HW-validated R2-R7).
// fragA: lane holds X[row=l&15][k=(l>>4)*8+j]; C: col=l&15, row=(l>>4)*4+r.
// Weights in XOR-swizzled LDS (byte ^= (row&7)<<4 within 128B rows): 2-way = free.
__global__ __launch_bounds__(256) void attn8(
    const float* __restrict__ q, const float* __restrict__ k,
    const float* __restrict__ v, const int* __restrict__ mask,
    const unsigned short* __restrict__ Mg, const unsigned short* __restrict__ vwg,
    unsigned short* __restrict__ X) {
  __shared__ char Mlb[8192];       // M, swizzled
  __shared__ char Vwb[8192];       // vw, swizzled
  __shared__ char scr_[4][2048];   // per-wave U/O scratch, swizzled

  const int tid = threadIdx.x;
  const int l = tid & 63, w = tid >> 6;
  const int lr = l & 15, lg = l >> 4;
  char* scr = scr_[w];

  // ---- stage weights, swizzled (512 16B-chunks per array) ----
#pragma unroll
  for (int i = 0; i < 2; ++i) {
    const int idx = tid + i * 256;
    const int row = idx >> 3, c = idx & 7;
    const int dst = row * 128 + ((c * 16) ^ ((row & 7) << 4));
    *(uint4*)(Mlb + dst) = *(const uint4*)(Mg + row * 64 + c * 8);
    *(uint4*)(Vwb + dst) = *(const uint4*)(vwg + row * 64 + c * 8);
  }
  __syncthreads();

  const int r7 = lr & 7;
  const int wc0 = (lg * 16) ^ (r7 << 4);         // weight frag byte col, k<32
  const int wc1 = (64 + lg * 16) ^ (r7 << 4);    // k>=32
  const int fr0 = lr * 128 + ((lg * 16) ^ (r7 << 4));       // scr frag offsets
  const int fr1 = lr * 128 + ((64 + lg * 16) ^ (r7 << 4));
  const int off = lr * 64 + lg * 8;

  const int tok0 = (blockIdx.x * 4 + w) * NT;

  float4 L[12];
  int4 Lm;
  {
    const size_t tb = (size_t)tok0 * 1024;
    L[0] = aload(q + tb + off);      L[1] = aload(q + tb + off + 4);
    L[2] = aload(q + tb + off + 32); L[3] = aload(q + tb + off + 36);
    L[4] = aload(k + tb + off);      L[5] = aload(k + tb + off + 4);
    L[6] = aload(k + tb + off + 32); L[7] = aload(k + tb + off + 36);
    L[8] = aload(v + tb + off);      L[9] = aload(v + tb + off + 4);
    L[10] = aload(v + tb + off + 32); L[11] = aload(v + tb + off + 36);
    Lm = aloadi(mask + (size_t)tok0 * 256 + lr * 16 + lg * 4);
  }

#pragma unroll
  for (int t = 0; t < NT; ++t) {
    const int tok = tok0 + t;

    // ---- wait for THIS token's 13 loads (leave next 13 + 2 stores in flight) ----
    if (t == 0) { WAITCNT(0); } else { WAITCNT(2); }
    SBAR();

    // ---- pack to bf16 frags (frees the 52 load regs) ----
    const bf16x8 aq0 = pack8(L[0], L[1]),  aq1 = pack8(L[2], L[3]);
    const bf16x8 ak0 = pack8(L[4], L[5]),  ak1 = pack8(L[6], L[7]);
    const bf16x8 av0 = pack8(L[8], L[9]),  av1 = pack8(L[10], L[11]);
    const int4 mk4 = Lm;
    SBAR();

    // ---- issue next token's loads (overlap with compute below) ----
    if (t < NT - 1) {
      const size_t tb = (size_t)(tok + 1) * 1024;
      L[0] = aload(q + tb + off);      L[1] = aload(q + tb + off + 4);
      L[2] = aload(q + tb + off + 32); L[3] = aload(q + tb + off + 36);
      L[4] = aload(k + tb + off);      L[5] = aload(k + tb + off + 4);
      L[6] = aload(k + tb + off + 32); L[7] = aload(k + tb + off + 36);
      L[8] = aload(v + tb + off);      L[9] = aload(v + tb + off + 4);
      L[10] = aload(v + tb + off + 32); L[11] = aload(v + tb + off + 36);
      Lm = aloadi(mask + (size_t)(tok + 1) * 256 + lr * 16 + lg * 4);
    }
    SBAR();

    // ---- U = Rk @ M^T ; v4 = Rv @ vw^T ----
    f32x4 accu[4], accv[4];
#pragma unroll
    for (int n = 0; n < 4; ++n) {
      const int wrow = (n * 16 + lr) * 128;
      f32x4 z = {};
      const bf16x8 bm0 = *(const bf16x8*)(Mlb + wrow + wc0);
      const bf16x8 bm1 = *(const bf16x8*)(Mlb + wrow + wc1);
      accu[n] = __builtin_amdgcn_mfma_f32_16x16x32_bf16(ak0, bm0, z, 0, 0, 0);
      accu[n] = __builtin_amdgcn_mfma_f32_16x16x32_bf16(ak1, bm1, accu[n], 0, 0, 0);
      const bf16x8 bw0 = *(const bf16x8*)(Vwb + wrow + wc0);
      const bf16x8 bw1 = *(const bf16x8*)(Vwb + wrow + wc1);
      accv[n] = __builtin_amdgcn_mfma_f32_16x16x32_bf16(av0, bw0, z, 0, 0, 0);
      accv[n] = __builtin_amdgcn_mfma_f32_16x16x32_bf16(av1, bw1, accv[n], 0, 0, 0);
    }

    // ---- U -> swizzled scratch, re-read as A-frag, S^T = U @ Rq^T ----
#pragma unroll
    for (int n = 0; n < 4; ++n)
#pragma unroll
      for (int r = 0; r < 4; ++r) {
        const int row = lg * 4 + r;
        *(unsigned short*)(scr + row * 128 + ((32 * n + 2 * lr) ^ ((row & 7) << 4))) =
            f2bf(accu[n][r]);
      }
    const bf16x8 ua0 = *(const bf16x8*)(scr + fr0);
    const bf16x8 ua1 = *(const bf16x8*)(scr + fr1);
    f32x4 z4 = {};
    f32x4 st = __builtin_amdgcn_mfma_f32_16x16x32_bf16(ua0, aq0, z4, 0, 0, 0);
    st = __builtin_amdgcn_mfma_f32_16x16x32_bf16(ua1, aq1, st, 0, 0, 0);

    // ---- softmax over g (no max-subtraction: |S| small; masked -> 0) ----
    float e[4];
    float sm = 0.f;
    const int mks[4] = {mk4.x, mk4.y, mk4.z, mk4.w};
#pragma unroll
    for (int r = 0; r < 4; ++r) {
      e[r] = (mks[r] != 0) ? __expf(st[r] * 0.125f) : 0.f;
      sm += e[r];
    }
    sm += __shfl_xor(sm, 16);
    sm += __shfl_xor(sm, 32);
    const float inv = 1.0f / sm;
#pragma unroll
    for (int r = 0; r < 4; ++r) e[r] *= inv;

    // ---- PV A-frag (P[h=lr][g=lg*8+j], lanes lg>=2 zero) ----
    bf16x8 apv;
#pragma unroll
    for (int j = 0; j < 8; ++j) {
      const int srcg = (lg * 2 + (j >> 2)) & 3;
      const float pv = __shfl(e[j & 3], lr + srcg * 16, 64);
      apv[j] = (short)((lg < 2) ? f2bf(pv) : (unsigned short)0);
    }

    // ---- PV B-frags from accv via shuffles; O = P @ v4 ----
    const int s0 = lr + ((lg & 1) * 2) * 16;
    const int s1 = s0 + 16;
    f32x4 o[4];
#pragma unroll
    for (int n = 0; n < 4; ++n) {
      bf16x8 bv;
#pragma unroll
      for (int j = 0; j < 8; ++j) {
        const float xv = __shfl(accv[n][j & 3], (j < 4) ? s0 : s1, 64);
        bv[j] = (short)f2bf(xv);
      }
      f32x4 z = {};
      o[n] = __builtin_amdgcn_mfma_f32_16x16x32_bf16(apv, bv, z, 0, 0, 0);
    }

    // ---- O -> swizzled scratch -> vectorized X stores (2 per lane) ----
#pragma unroll
    for (int n = 0; n < 4; ++n)
#pragma unroll
      for (int r = 0; r < 4; ++r) {
        const int row = lg * 4 + r;
        *(unsigned short*)(scr + row * 128 + ((32 * n + 2 * lr) ^ ((row & 7) << 4))) =
            f2bf(o[n][r]);
      }
    const int nb = tok >> 12, lpos = tok & (LSEQ - 1);
#pragma unroll
    for (int it = 0; it < 2; ++it) {
      const int idx = it * 64 + l;
      const int h = idx >> 3, c = idx & 7;
      const uint4 val = *(const uint4*)(scr + h * 128 + ((c * 16) ^ ((h & 7) << 4)));
      *(uint4*)&X[((size_t)(nb * 16 + h) * LSEQ + lpos) * 64 + c * 8] = val;
    }
  }
}

// ---------------- final FC: OUT[16384x1024] = X @ fc_w^T + b (bf16 MFMA) ----------------
__global__ __launch_bounds__(256) void gemm_fc(const unsigned short* __restrict__ A,
                                               const unsigned short* __restrict__ B,
                                               const float* __restrict__ bias,
                                               float* __restrict__ C) {
  __shared__ unsigned short sA[128 * 32];
  __shared__ unsigned short sB[128 * 32];
  const int tid = threadIdx.x;
  const int l = tid & 63, w = tid >> 6;
  const int wr = w >> 1, wc = w & 1;

  const int bid = blockIdx.x;
  const int wg = (bid & 7) * 128 + (bid >> 3);
  const int tm = (wg >> 3) * 128;
  const int tn = (wg & 7) * 128;

  f32x4 acc[4][4] = {};

  const int r0 = w * 16 + (l >> 2);
  const int c8 = (l & 3) * 8;

  for (int kt = 0; kt < 32; ++kt) {
    const int k0 = kt * 32;
#pragma unroll
    for (int s = 0; s < 2; ++s) {
      async16(A + (size_t)(tm + s * 64 + r0) * 1024 + k0 + c8,
              (char*)sA + s * 4096 + w * 1024);
      async16(B + (size_t)(tn + s * 64 + r0) * 1024 + k0 + c8,
              (char*)sB + s * 4096 + w * 1024);
    }
    __syncthreads();

    bf16x8 af[4], bfr[4];
#pragma unroll
    for (int fi = 0; fi < 4; ++fi)
      af[fi] = *(const bf16x8*)((const char*)sA +
                                (wr * 64 + fi * 16 + (l & 15)) * 64 + (l >> 4) * 16);
#pragma unroll
    for (int fj = 0; fj < 4; ++fj)
      bfr[fj] = *(const bf16x8*)((const char*)sB +
                                 (wc * 64 + fj * 16 + (l & 15)) * 64 + (l >> 4) * 16);
#pragma unroll
    for (int fi = 0; fi < 4; ++fi)
#pragma unroll
      for (int fj = 0; fj < 4; ++fj)
        acc[fi][fj] = __builtin_amdgcn_mfma_f32_16x16x32_bf16(af[fi], bfr[fj],
                                                              acc[fi][fj], 0, 0, 0);
    __syncthreads();
  }

#pragma unroll
  for (int fj = 0; fj < 4; ++fj) {
    const int col = tn + wc * 64 + fj * 16 + (l & 15);
    const float bv = bias[col];
#pragma unroll
    for (int fi = 0; fi < 4; ++fi) {
#pragma unroll
      for (int r = 0; r < 4; ++r) {
        const int row = tm + wr * 64 + fi * 16 + (l >> 4) * 4 + r;
        C[(size_t)row * 1024 + col] = acc[fi][fj][r] + bv;
      }
    }
  }
}

extern "C" void kernel_launch(void* const* d_in, const int* in_sizes, int n_in,
                              void* d_out, int out_size, void* d_ws, size_t ws_size,
                              hipStream_t stream) {
  (void)in_sizes; (void)n_in; (void)out_size; (void)ws_size;
  const float* q   = (const float*)d_in[0];
  const float* k   = (const float*)d_in[1];
  const float* v   = (const float*)d_in[2];
  const int*  mask = (const int*)d_in[3];
  const float* qw  = (const float*)d_in[4];
  const float* kw  = (const float*)d_in[5];
  const float* vw  = (const float*)d_in[6];
  const float* fcw = (const float*)d_in[7];
  const float* fcb = (const float*)d_in[8];
  float* out = (float*)d_out;

  unsigned short* X   = (unsigned short*)d_ws;            // 16M bf16 = 32 MiB
  unsigned short* Wb  = X + (size_t)16 * 1024 * 1024;     // 1M bf16  =  2 MiB
  unsigned short* Mw  = Wb + (size_t)1024 * 1024;         // 4096 bf16 = 8 KiB
  unsigned short* vwb = Mw + 4096;                        // 4096 bf16 = 8 KiB

  cvt_bf16<<<dim3(1024), dim3(256), 0, stream>>>(fcw, Wb, 262144);
  prep_weights<<<dim3(1), dim3(1024), 0, stream>>>(qw, kw, vw, Mw, vwb);
  attn8<<<dim3(1024), dim3(256), 0, stream>>>(q, k, v, mask, Mw, vwb, X);
  gemm_fc<<<dim3(1024), dim3(256), 0, stream>>>(X, Wb, fcb, out);
}